// Round 21
// baseline (197.815 us; speedup 1.0000x reference)
//
#include <hip/hip_runtime.h>
#include <hip/hip_fp16.h>

static constexpr int IN_F = 128;
static constexpr int FCAP = 6144;   // staged records per bucket

typedef _Float16 half8 __attribute__((ext_vector_type(8)));
typedef _Float16 half4 __attribute__((ext_vector_type(4)));
typedef float f32x4 __attribute__((ext_vector_type(4)));
typedef float f32x2 __attribute__((ext_vector_type(2)));

// ---- fp8 e4m3 helpers (HW cvt; self-consistent encode/decode) ----
__device__ inline void acc_fp8x8(uint2 u, f32x2* a) {
    a[0] += __builtin_amdgcn_cvt_pk_f32_fp8(u.x, false);
    a[1] += __builtin_amdgcn_cvt_pk_f32_fp8(u.x, true);
    a[2] += __builtin_amdgcn_cvt_pk_f32_fp8(u.y, false);
    a[3] += __builtin_amdgcn_cvt_pk_f32_fp8(u.y, true);
}
__device__ inline void acc_fp8x4(unsigned u, f32x2* a) {
    a[0] += __builtin_amdgcn_cvt_pk_f32_fp8(u, false);
    a[1] += __builtin_amdgcn_cvt_pk_f32_fp8(u, true);
}
__device__ inline void fp8x8_to_f32(uint2 u, float* f) {
    f32x2 a0 = __builtin_amdgcn_cvt_pk_f32_fp8(u.x, false);
    f32x2 a1 = __builtin_amdgcn_cvt_pk_f32_fp8(u.x, true);
    f32x2 a2 = __builtin_amdgcn_cvt_pk_f32_fp8(u.y, false);
    f32x2 a3 = __builtin_amdgcn_cvt_pk_f32_fp8(u.y, true);
    f[0] = a0[0]; f[1] = a0[1]; f[2] = a1[0]; f[3] = a1[1];
    f[4] = a2[0]; f[5] = a2[1]; f[6] = a3[0]; f[7] = a3[1];
}
__device__ inline void fp8x4_to_f32(unsigned u, float* f) {
    f32x2 a0 = __builtin_amdgcn_cvt_pk_f32_fp8(u, false);
    f32x2 a1 = __builtin_amdgcn_cvt_pk_f32_fp8(u, true);
    f[0] = a0[0]; f[1] = a0[1]; f[2] = a1[0]; f[3] = a1[1];
}
__device__ inline unsigned char f32_to_fp8(float v) {
    return (unsigned char)__builtin_amdgcn_cvt_pk_fp8_f32(v, v, 0, false);
}

// ================= bucketed CSR build =================
// bucket b = dst >> 8 (256 nodes/bucket); record = (dstLow:8 << 17) | src:17

__global__ __launch_bounds__(1024) void kb_count(const int* __restrict__ dst,
                                                 int* __restrict__ bcount, int E) {
    __shared__ int cnt[16][512];   // per-wave banks, 32 KB
    const int tid = threadIdx.x;
    const int wv  = tid >> 6;
    for (int i = tid; i < 16 * 512; i += 1024) (&cnt[0][0])[i] = 0;
    __syncthreads();
#pragma unroll
    for (int q = 0; q < 8; ++q) {
        int i = blockIdx.x * 8192 + q * 1024 + tid;
        if (i < E) atomicAdd(&cnt[wv][dst[i] >> 8], 1);
    }
    __syncthreads();
    if (tid < 512) {
        int run = 0;
#pragma unroll
        for (int w = 0; w < 16; ++w) run += cnt[w][tid];
        if (run > 0) atomicAdd(&bcount[tid], run);
    }
}

__global__ __launch_bounds__(512) void k_scanb(const int* __restrict__ bcount,
                                               int* __restrict__ bbase,
                                               int* __restrict__ bcursor, int NB) {
    __shared__ int s[512];
    const int tid = threadIdx.x;
    int v = (tid < NB) ? bcount[tid] : 0;
    s[tid] = v;
    __syncthreads();
    int inc = v;
#pragma unroll
    for (int off = 1; off < 512; off <<= 1) {
        int add = (tid >= off) ? s[tid - off] : 0;
        __syncthreads();
        s[tid] = inc = inc + add;
        __syncthreads();
    }
    if (tid < NB) { bbase[tid] = inc - v; bcursor[tid] = inc - v; }
    if (tid == NB - 1) bbase[NB] = inc;
}

__global__ __launch_bounds__(1024) void kb_move(const int* __restrict__ src,
                                                const int* __restrict__ dst,
                                                int* __restrict__ bcursor,
                                                unsigned* __restrict__ recs, int E) {
    __shared__ int cnt[16][512];   // per-wave banks: counts -> wave prefixes -> cursors
    __shared__ int gbase[512];
    const int tid = threadIdx.x;
    const int wv  = tid >> 6;
    for (int i = tid; i < 16 * 512; i += 1024) (&cnt[0][0])[i] = 0;
    __syncthreads();

    int bq[8];
    unsigned rq[8];
#pragma unroll
    for (int q = 0; q < 8; ++q) {
        int i = blockIdx.x * 8192 + q * 1024 + tid;
        if (i < E) {
            int d = dst[i];
            int s = src[i];
            bq[q] = d >> 8;
            rq[q] = (unsigned)(((d & 255) << 17) | s);
            atomicAdd(&cnt[wv][bq[q]], 1);
        } else {
            bq[q] = -1;
            rq[q] = 0u;
        }
    }
    __syncthreads();
    if (tid < 512) {
        int run = 0;
#pragma unroll
        for (int w = 0; w < 16; ++w) {
            int t = cnt[w][tid];
            cnt[w][tid] = run;
            run += t;
        }
        gbase[tid] = (run > 0) ? atomicAdd(&bcursor[tid], run) : 0;
    }
    __syncthreads();
#pragma unroll
    for (int q = 0; q < 8; ++q) {
        if (bq[q] >= 0) {
            int p = gbase[bq[q]] + atomicAdd(&cnt[wv][bq[q]], 1);
            recs[p] = rq[q];
        }
    }
}

// one block (512 thr) per bucket: 2048-bin sort (dstLow<<3 | srcPartition)
// -> csr is partition-ordered within each node's segment (L2 phase locality).
__global__ __launch_bounds__(512) void kb_fill_lds(const unsigned* __restrict__ recs,
                                                   const int* __restrict__ bbase,
                                                   int* __restrict__ row_ptr,
                                                   float* __restrict__ dis,
                                                   int* __restrict__ csr, int n, int E) {
    __shared__ int hist[2048];
    __shared__ int wsum[512];
    __shared__ int base[2048];
    __shared__ int cur[2048];
    __shared__ int stage[FCAP];
    const int tid   = threadIdx.x;
    const int b     = blockIdx.x;
    const int s     = bbase[b], e = bbase[b + 1];
    const int nbase = b << 8;

    for (int i = tid; i < 2048; i += 512) hist[i] = 0;
    __syncthreads();
    for (int i = s + tid; i < e; i += 512) {
        unsigned r = recs[i];
        int dl = (int)(r >> 17);
        int sr = (int)(r & 0x1FFFFu);
        atomicAdd(&hist[(dl << 3) | (sr >> 14)], 1);
    }
    __syncthreads();

    // scan over 2048 bins: thread t owns bins 4t..4t+3
    const int l0 = hist[tid * 4 + 0];
    const int l1 = hist[tid * 4 + 1];
    const int l2 = hist[tid * 4 + 2];
    const int l3 = hist[tid * 4 + 3];
    const int tot = l0 + l1 + l2 + l3;
    wsum[tid] = tot;
    __syncthreads();
    int inc = tot;
#pragma unroll
    for (int off = 1; off < 512; off <<= 1) {
        int add = (tid >= off) ? wsum[tid - off] : 0;
        __syncthreads();
        wsum[tid] = inc = inc + add;
        __syncthreads();
    }
    int run = inc - tot;   // exclusive prefix of bin 4t
    base[tid * 4 + 0] = run; cur[tid * 4 + 0] = 0; run += l0;
    base[tid * 4 + 1] = run; cur[tid * 4 + 1] = 0; run += l1;
    base[tid * 4 + 2] = run; cur[tid * 4 + 2] = 0; run += l2;
    base[tid * 4 + 3] = run; cur[tid * 4 + 3] = 0; run += l3;
    __syncthreads();

    // row_ptr + dis at node level (node dl = bins dl*8..dl*8+7)
    if (tid < 256) {
        int cnt = 0;
#pragma unroll
        for (int q = 0; q < 8; ++q) cnt += hist[tid * 8 + q];
        const int idx = nbase + tid;
        if (idx < n) {
            row_ptr[idx] = s + base[tid * 8];
            dis[idx] = rsqrtf(1.0f + (float)cnt);
        }
        if (idx == n) row_ptr[n] = s + base[tid * 8];
        if (tid == 255 && nbase + 256 == n) row_ptr[n] = e;
    }
    __syncthreads();

    // place into LDS staging at sorted slot
    for (int i = s + tid; i < e; i += 512) {
        unsigned r = recs[i];
        int dl = (int)(r >> 17);
        int sr = (int)(r & 0x1FFFFu);
        int k  = (dl << 3) | (sr >> 14);
        int slot = base[k] + atomicAdd(&cur[k], 1);
        if (slot < FCAP) stage[slot] = sr;
        else csr[s + slot] = sr;
    }
    __syncthreads();

    const int total = e - s;
    const int lim = total < FCAP ? total : FCAP;
    for (int i = tid; i < lim; i += 512)
        csr[s + i] = stage[i];
}

// ================= weight prep: f32 [K][F] -> fp16 [F][K] =================
__global__ __launch_bounds__(256) void k_prep_w(const float* __restrict__ gW1,
                                                const float* __restrict__ mW1,
                                                const float* __restrict__ mW2,
                                                const float* __restrict__ gW2,
                                                _Float16* __restrict__ tg1,
                                                _Float16* __restrict__ tm1,
                                                _Float16* __restrict__ tm2,
                                                _Float16* __restrict__ tg2) {
    int i = blockIdx.x * 256 + threadIdx.x;
    if (i < 16384)      { int j = i;         int f = j >> 7, k = j & 127; tg1[j] = (_Float16)gW1[k * 128 + f]; }
    else if (i < 32768) { int j = i - 16384; int f = j >> 7, k = j & 127; tm1[j] = (_Float16)mW1[k * 128 + f]; }
    else if (i < 40960) { int j = i - 32768; int f = j >> 7, k = j & 127; tm2[j] = (_Float16)mW2[k * 64 + f]; }
    else if (i < 49152) { int j = i - 40960; int f = j >> 7, k = j & 127; tg2[j] = (_Float16)gW2[k * 64 + f]; }
}

// ============ fused MFMA: h1' = fp8(dis*(x@gW1)), z = relu(x@mW1+b1)@mW2+b2 ============
// LDS: As(16KB, aliased as Ms) + Ws(16KB half-staged) = 32 KB.
__global__ __launch_bounds__(256) void k_dual_mfma(const float* __restrict__ x,
                                                   const _Float16* __restrict__ tg1,
                                                   const _Float16* __restrict__ tm1,
                                                   const _Float16* __restrict__ tm2,
                                                   const float* __restrict__ b1,
                                                   const float* __restrict__ b2,
                                                   const float* __restrict__ dis,
                                                   unsigned char* __restrict__ h1,
                                                   _Float16* __restrict__ z, int nrows) {
    __shared__ _Float16 As[64 * 128];    // 16 KB (x fragments, later Ms)
    __shared__ _Float16 Ws[64 * 128];    // 16 KB (64 W rows at a time)
    _Float16* Ms = As;
    const int tid  = threadIdx.x;
    const int row0 = blockIdx.x * 64;

#pragma unroll
    for (int p = 0; p < 4; ++p) {
        int sid = p * 256 + tid;
        int r = sid >> 4, s = sid & 15;
        int gr = row0 + r;
        uint4 v = make_uint4(0, 0, 0, 0);
        if (gr < nrows) {
            const float4 f0 = *reinterpret_cast<const float4*>(x + (size_t)gr * 128 + s * 8);
            const float4 f1 = *reinterpret_cast<const float4*>(x + (size_t)gr * 128 + s * 8 + 4);
            _Float16 t[8] = {(_Float16)f0.x, (_Float16)f0.y, (_Float16)f0.z, (_Float16)f0.w,
                             (_Float16)f1.x, (_Float16)f1.y, (_Float16)f1.z, (_Float16)f1.w};
            v = *reinterpret_cast<uint4*>(t);
        }
        *reinterpret_cast<uint4*>(&As[r * 128 + ((s ^ (r & 7)) * 8)]) = v;
    }

    const int lane = tid & 63;
    const int wv   = tid >> 6;
    const int mrow = wv * 16 + (lane & 15);
    const int kg   = lane >> 4;
    const int grow = row0 + wv * 16 + kg * 4;

    auto stageW = [&](const _Float16* Wt, int wbase) {
#pragma unroll
        for (int p = 0; p < 4; ++p) {
            int sid = p * 256 + tid;
            int r = sid >> 4, s = sid & 15;
            uint4 v = *reinterpret_cast<const uint4*>(Wt + (size_t)(wbase + r) * 128 + s * 8);
            *reinterpret_cast<uint4*>(&Ws[r * 128 + ((s ^ (r & 7)) * 8)]) = v;
        }
    };

    stageW(tg1, 0);
    __syncthreads();

    half8 a[4];
#pragma unroll
    for (int kk = 0; kk < 4; ++kk)
        a[kk] = *reinterpret_cast<const half8*>(&As[mrow * 128 + (((kk * 4 + kg) ^ (mrow & 7)) * 8)]);

    float dvals[4];
#pragma unroll
    for (int j = 0; j < 4; ++j)
        dvals[j] = (grow + j < nrows) ? dis[grow + j] : 0.f;

    // phase 1: h1' = fp8(dis * (x @ gW1)), two column-half sub-phases
#pragma unroll
    for (int half = 0; half < 2; ++half) {
        if (half == 1) {
            __syncthreads();
            stageW(tg1, 64);
            __syncthreads();
        }
#pragma unroll
        for (int ct = 0; ct < 4; ++ct) {
            const int ncol = half * 64 + ct * 16 + (lane & 15);
            const int wrow = ncol & 63;
            f32x4 acc = {0.f, 0.f, 0.f, 0.f};
#pragma unroll
            for (int kk = 0; kk < 4; ++kk) {
                half8 b = *reinterpret_cast<const half8*>(&Ws[wrow * 128 + (((kk * 4 + kg) ^ (wrow & 7)) * 8)]);
                acc = __builtin_amdgcn_mfma_f32_16x16x32_f16(a[kk], b, acc, 0, 0, 0);
            }
#pragma unroll
            for (int j = 0; j < 4; ++j)
                if (grow + j < nrows)
                    h1[(size_t)(grow + j) * 128 + ncol] = f32_to_fp8(acc[j] * dvals[j]);
        }
    }
    __syncthreads();

    // phase 2: M = relu(x@mW1 + b1) -> Ms (=As region; a[] already in regs)
#pragma unroll
    for (int half = 0; half < 2; ++half) {
        stageW(tm1, half * 64);
        __syncthreads();
#pragma unroll
        for (int ct = 0; ct < 4; ++ct) {
            const int ncol = half * 64 + ct * 16 + (lane & 15);
            const int wrow = ncol & 63;
            f32x4 acc = {0.f, 0.f, 0.f, 0.f};
#pragma unroll
            for (int kk = 0; kk < 4; ++kk) {
                half8 b = *reinterpret_cast<const half8*>(&Ws[wrow * 128 + (((kk * 4 + kg) ^ (wrow & 7)) * 8)]);
                acc = __builtin_amdgcn_mfma_f32_16x16x32_f16(a[kk], b, acc, 0, 0, 0);
            }
            const float bias = b1[ncol];
#pragma unroll
            for (int j = 0; j < 4; ++j) {
                int r = wv * 16 + kg * 4 + j;
                float v = fmaxf((float)acc[j] + bias, 0.f);
                Ms[r * 128 + (((ncol >> 3) ^ (r & 7)) * 8) + (ncol & 7)] = (_Float16)v;
            }
        }
        __syncthreads();
    }

    // phase 3: z = M @ mW2 + b2 (F=64)
    stageW(tm2, 0);
    __syncthreads();

    half8 am[4];
#pragma unroll
    for (int kk = 0; kk < 4; ++kk)
        am[kk] = *reinterpret_cast<const half8*>(&Ms[mrow * 128 + (((kk * 4 + kg) ^ (mrow & 7)) * 8)]);

#pragma unroll
    for (int ct = 0; ct < 4; ++ct) {
        const int ncol = ct * 16 + (lane & 15);
        f32x4 acc = {0.f, 0.f, 0.f, 0.f};
#pragma unroll
        for (int kk = 0; kk < 4; ++kk) {
            half8 b = *reinterpret_cast<const half8*>(&Ws[ncol * 128 + (((kk * 4 + kg) ^ (ncol & 7)) * 8)]);
            acc = __builtin_amdgcn_mfma_f32_16x16x32_f16(am[kk], b, acc, 0, 0, 0);
        }
        const float bias = b2[ncol];
#pragma unroll
        for (int j = 0; j < 4; ++j)
            if (grow + j < nrows)
                z[(size_t)(grow + j) * 64 + ncol] = (_Float16)((float)acc[j] + bias);
    }
}

// ============ MFMA GEMM: h2' = fp8(dis * (hmid @ gW2)), F=64; W in LDS ============
__global__ __launch_bounds__(256) void k_mm64(const _Float16* __restrict__ A,
                                              const _Float16* __restrict__ Wt,
                                              const float* __restrict__ dis,
                                              unsigned char* __restrict__ C, int nrows) {
    __shared__ _Float16 As[64 * 128];
    __shared__ _Float16 Ws[64 * 128];
    const int tid  = threadIdx.x;
    const int row0 = blockIdx.x * 64;

#pragma unroll
    for (int p = 0; p < 4; ++p) {
        int sid = p * 256 + tid;
        int r = sid >> 4, s = sid & 15;
        int gr = row0 + r;
        uint4 v = make_uint4(0, 0, 0, 0);
        if (gr < nrows) v = *reinterpret_cast<const uint4*>(A + (size_t)gr * 128 + s * 8);
        *reinterpret_cast<uint4*>(&As[r * 128 + ((s ^ (r & 7)) * 8)]) = v;
    }
#pragma unroll
    for (int p = 0; p < 4; ++p) {
        int sid = p * 256 + tid;
        int r = sid >> 4, s = sid & 15;
        uint4 v = *reinterpret_cast<const uint4*>(Wt + (size_t)r * 128 + s * 8);
        *reinterpret_cast<uint4*>(&Ws[r * 128 + ((s ^ (r & 7)) * 8)]) = v;
    }
    __syncthreads();

    const int lane = tid & 63;
    const int wv   = tid >> 6;
    const int mrow = wv * 16 + (lane & 15);
    const int kg   = lane >> 4;
    const int grow = row0 + wv * 16 + kg * 4;

    half8 a[4];
#pragma unroll
    for (int kk = 0; kk < 4; ++kk)
        a[kk] = *reinterpret_cast<const half8*>(&As[mrow * 128 + (((kk * 4 + kg) ^ (mrow & 7)) * 8)]);

    float dvals[4];
#pragma unroll
    for (int j = 0; j < 4; ++j)
        dvals[j] = (grow + j < nrows) ? dis[grow + j] : 0.f;

#pragma unroll
    for (int ct = 0; ct < 4; ++ct) {
        const int ncol = ct * 16 + (lane & 15);
        f32x4 acc = {0.f, 0.f, 0.f, 0.f};
#pragma unroll
        for (int kk = 0; kk < 4; ++kk) {
            half8 b = *reinterpret_cast<const half8*>(&Ws[ncol * 128 + (((kk * 4 + kg) ^ (ncol & 7)) * 8)]);
            acc = __builtin_amdgcn_mfma_f32_16x16x32_f16(a[kk], b, acc, 0, 0, 0);
        }
#pragma unroll
        for (int j = 0; j < 4; ++j)
            if (grow + j < nrows)
                C[(size_t)(grow + j) * 64 + ncol] = f32_to_fp8(acc[j] * dvals[j]);
    }
}

// ================= gather aggregation (sorted CSR + 4-way edge groups) =================
// layer 1: F=128; out = relu(dd * (sum_j h1'[s_j] + h1'[node]) + b), hmid fp16
__global__ __launch_bounds__(256) void k_agg1(const int* __restrict__ rp,
                                              const int* __restrict__ csr,
                                              const float* __restrict__ dis,
                                              const unsigned char* __restrict__ h1,
                                              const float* __restrict__ b,
                                              _Float16* __restrict__ out, int n) {
    const int tid  = threadIdx.x;
    const int node = blockIdx.x * 4 + (tid >> 6);
    if (node >= n) return;
    const int lane = tid & 63;
    const int g    = lane >> 4;          // edge group 0..3
    const int c0   = (lane & 15) * 8;    // 8 fp8 feature bytes per lane
    const int start = rp[node], end = rp[node + 1];

    f32x2 acc[4] = {{0.f, 0.f}, {0.f, 0.f}, {0.f, 0.f}, {0.f, 0.f}};

    int j = start + g;
    for (; j + 12 < end; j += 16) {
        int s0 = csr[j];
        int s1 = csr[j + 4];
        int s2 = csr[j + 8];
        int s3 = csr[j + 12];
        uint2 u0 = *reinterpret_cast<const uint2*>(h1 + (size_t)s0 * 128 + c0);
        uint2 u1 = *reinterpret_cast<const uint2*>(h1 + (size_t)s1 * 128 + c0);
        uint2 u2 = *reinterpret_cast<const uint2*>(h1 + (size_t)s2 * 128 + c0);
        uint2 u3 = *reinterpret_cast<const uint2*>(h1 + (size_t)s3 * 128 + c0);
        acc_fp8x8(u0, acc);
        acc_fp8x8(u1, acc);
        acc_fp8x8(u2, acc);
        acc_fp8x8(u3, acc);
    }
    for (; j < end; j += 4) {
        int s0 = csr[j];
        uint2 u0 = *reinterpret_cast<const uint2*>(h1 + (size_t)s0 * 128 + c0);
        acc_fp8x8(u0, acc);
    }

    float av[8] = {acc[0][0], acc[0][1], acc[1][0], acc[1][1],
                   acc[2][0], acc[2][1], acc[3][0], acc[3][1]};
#pragma unroll
    for (int k = 0; k < 8; ++k) {
        av[k] += __shfl_xor(av[k], 16);
        av[k] += __shfl_xor(av[k], 32);
    }

    if (g == 0) {
        const float dd = dis[node];
        uint2 un = *reinterpret_cast<const uint2*>(h1 + (size_t)node * 128 + c0);
        float fn[8];
        fp8x8_to_f32(un, fn);
        const float4 bv0 = *reinterpret_cast<const float4*>(b + c0);
        const float4 bv1 = *reinterpret_cast<const float4*>(b + c0 + 4);
        const float bb[8] = {bv0.x, bv0.y, bv0.z, bv0.w, bv1.x, bv1.y, bv1.z, bv1.w};
        half8 o;
#pragma unroll
        for (int k = 0; k < 8; ++k)
            o[k] = (_Float16)fmaxf(dd * (av[k] + fn[k]) + bb[k], 0.f);
        *reinterpret_cast<half8*>(out + (size_t)node * 128 + c0) = o;
    }
}

// layer 2 + final fuse: F=64; out = 0.5*((dd*(sum + h2'[node]) + b) + zmlp)
__global__ __launch_bounds__(256) void k_agg2(const int* __restrict__ rp,
                                              const int* __restrict__ csr,
                                              const float* __restrict__ dis,
                                              const unsigned char* __restrict__ h2,
                                              const float* __restrict__ b,
                                              const _Float16* __restrict__ zmlp,
                                              float* __restrict__ out, int n) {
    const int tid  = threadIdx.x;
    const int node = blockIdx.x * 4 + (tid >> 6);
    if (node >= n) return;
    const int lane = tid & 63;
    const int g    = lane >> 4;
    const int c0   = (lane & 15) * 4;    // 4 fp8 bytes per lane
    const int start = rp[node], end = rp[node + 1];

    f32x2 acc[2] = {{0.f, 0.f}, {0.f, 0.f}};

    int j = start + g;
    for (; j + 12 < end; j += 16) {
        int s0 = csr[j];
        int s1 = csr[j + 4];
        int s2 = csr[j + 8];
        int s3 = csr[j + 12];
        unsigned u0 = *reinterpret_cast<const unsigned*>(h2 + (size_t)s0 * 64 + c0);
        unsigned u1 = *reinterpret_cast<const unsigned*>(h2 + (size_t)s1 * 64 + c0);
        unsigned u2 = *reinterpret_cast<const unsigned*>(h2 + (size_t)s2 * 64 + c0);
        unsigned u3 = *reinterpret_cast<const unsigned*>(h2 + (size_t)s3 * 64 + c0);
        acc_fp8x4(u0, acc);
        acc_fp8x4(u1, acc);
        acc_fp8x4(u2, acc);
        acc_fp8x4(u3, acc);
    }
    for (; j < end; j += 4) {
        int s0 = csr[j];
        unsigned u0 = *reinterpret_cast<const unsigned*>(h2 + (size_t)s0 * 64 + c0);
        acc_fp8x4(u0, acc);
    }

    float av[4] = {acc[0][0], acc[0][1], acc[1][0], acc[1][1]};
#pragma unroll
    for (int k = 0; k < 4; ++k) {
        av[k] += __shfl_xor(av[k], 16);
        av[k] += __shfl_xor(av[k], 32);
    }

    if (g == 0) {
        const float dd = dis[node];
        unsigned un = *reinterpret_cast<const unsigned*>(h2 + (size_t)node * 64 + c0);
        float fn[4];
        fp8x4_to_f32(un, fn);
        half4 zm = *reinterpret_cast<const half4*>(zmlp + (size_t)node * 64 + c0);
        const float4 bv = *reinterpret_cast<const float4*>(b + c0);
        const float bb[4] = {bv.x, bv.y, bv.z, bv.w};
        float4 o;
        float* op = &o.x;
#pragma unroll
        for (int k = 0; k < 4; ++k)
            op[k] = 0.5f * ((dd * (av[k] + fn[k]) + bb[k]) + (float)zm[k]);
        *reinterpret_cast<float4*>(out + (size_t)node * 64 + c0) = o;
    }
}

extern "C" void kernel_launch(void* const* d_in, const int* in_sizes, int n_in,
                              void* d_out, int out_size, void* d_ws, size_t ws_size,
                              hipStream_t stream) {
    const float* x      = (const float*)d_in[0];
    const int* edge_idx = (const int*)d_in[1];
    const float* gnn_W1 = (const float*)d_in[2];
    const float* gnn_b1 = (const float*)d_in[3];
    const float* gnn_W2 = (const float*)d_in[4];
    const float* gnn_b2 = (const float*)d_in[5];
    const float* mlp_W1 = (const float*)d_in[6];
    const float* mlp_b1 = (const float*)d_in[7];
    const float* mlp_W2 = (const float*)d_in[8];
    const float* mlp_b2 = (const float*)d_in[9];
    float* out = (float*)d_out;

    const int N = in_sizes[0] / IN_F;
    const int E = in_sizes[1] / 2;
    const int* src = edge_idx;
    const int* dst = edge_idx + E;

    const int NB = (N + 255) >> 8;   // 256-node buckets

    // ---- workspace layout ----
    char* wp = (char*)d_ws;
    int* row_ptr   = (int*)wp;            wp += ((size_t)N + 4) * sizeof(int);
    int* bbase     = (int*)wp;            wp += 516 * sizeof(int);
    int* bcursor   = (int*)wp;            wp += 512 * sizeof(int);
    int* bcount    = (int*)wp;            wp += 512 * sizeof(int);
    int* csr       = (int*)wp;            wp += (size_t)E * sizeof(int);
    unsigned* recs = (unsigned*)wp;       wp += (size_t)E * sizeof(unsigned);
    float* dis     = (float*)wp;          wp += (size_t)N * sizeof(float);
    _Float16* tg1  = (_Float16*)wp;       wp += 16384 * sizeof(_Float16);
    _Float16* tm1  = (_Float16*)wp;       wp += 16384 * sizeof(_Float16);
    _Float16* tm2  = (_Float16*)wp;       wp += 8192 * sizeof(_Float16);
    _Float16* tg2  = (_Float16*)wp;       wp += 8192 * sizeof(_Float16);
    unsigned char* h1 = (unsigned char*)wp;  wp += (size_t)N * 128;            // fp8
    _Float16* hmid = (_Float16*)wp;       wp += (size_t)N * 128 * sizeof(_Float16);
    unsigned char* h2 = (unsigned char*)wp;  wp += (size_t)N * 64;             // fp8
    wp = (char*)(((uintptr_t)wp + 15) & ~(uintptr_t)15);
    _Float16* zmlp = (_Float16*)wp;       wp += (size_t)N * 64 * sizeof(_Float16);

    // ---- weight prep ----
    k_prep_w<<<192, 256, 0, stream>>>(gnn_W1, mlp_W1, mlp_W2, gnn_W2, tg1, tm1, tm2, tg2);

    // ---- bucketed CSR build (partition-ordered within node) ----
    hipMemsetAsync(bcount, 0, 512 * sizeof(int), stream);
    const int mvblocks = (E + 8191) / 8192;
    kb_count<<<mvblocks, 1024, 0, stream>>>(dst, bcount, E);
    k_scanb<<<1, 512, 0, stream>>>(bcount, bbase, bcursor, NB);
    kb_move<<<mvblocks, 1024, 0, stream>>>(src, dst, bcursor, recs, E);
    kb_fill_lds<<<NB, 512, 0, stream>>>(recs, bbase, row_ptr, dis, csr, N, E);

    const int gblocks = (N + 63) / 64;
    const int ablocks = (N + 3) / 4;

    // ---- fused: h1' = fp8(dis*(x@gW1)), zmlp = MLP(x) (one x pass; 32KB LDS) ----
    k_dual_mfma<<<gblocks, 256, 0, stream>>>(x, tg1, tm1, tm2, mlp_b1, mlp_b2, dis, h1, zmlp, N);

    // ---- GNN layer 1 aggregation (sorted CSR, 4 edges in flight per group set) ----
    k_agg1<<<ablocks, 256, 0, stream>>>(row_ptr, csr, dis, h1, gnn_b1, hmid, N);

    // ---- h2' = fp8(dis*(hmid @ gW2)) (MFMA) ----
    k_mm64<<<gblocks, 256, 0, stream>>>(hmid, tg2, dis, h2, N);

    // ---- layer-2 aggregation fused with final mix ----
    k_agg2<<<ablocks, 256, 0, stream>>>(row_ptr, csr, dis, h2, gnn_b2, zmlp, out, N);
}

// Round 22
// 177.380 us; speedup vs baseline: 1.1152x; 1.1152x over previous
//
#include <hip/hip_runtime.h>
#include <hip/hip_fp16.h>

static constexpr int IN_F = 128;
static constexpr int FCAP = 6144;   // staged records per bucket

typedef _Float16 half8 __attribute__((ext_vector_type(8)));
typedef _Float16 half4 __attribute__((ext_vector_type(4)));
typedef float f32x4 __attribute__((ext_vector_type(4)));
typedef float f32x2 __attribute__((ext_vector_type(2)));

// ---- fp8 e4m3 helpers (HW cvt; self-consistent encode/decode) ----
__device__ inline void acc_fp8x8(uint2 u, f32x2* a) {
    a[0] += __builtin_amdgcn_cvt_pk_f32_fp8(u.x, false);
    a[1] += __builtin_amdgcn_cvt_pk_f32_fp8(u.x, true);
    a[2] += __builtin_amdgcn_cvt_pk_f32_fp8(u.y, false);
    a[3] += __builtin_amdgcn_cvt_pk_f32_fp8(u.y, true);
}
__device__ inline void acc_fp8x4(unsigned u, f32x2* a) {
    a[0] += __builtin_amdgcn_cvt_pk_f32_fp8(u, false);
    a[1] += __builtin_amdgcn_cvt_pk_f32_fp8(u, true);
}
__device__ inline void fp8x8_to_f32(uint2 u, float* f) {
    f32x2 a0 = __builtin_amdgcn_cvt_pk_f32_fp8(u.x, false);
    f32x2 a1 = __builtin_amdgcn_cvt_pk_f32_fp8(u.x, true);
    f32x2 a2 = __builtin_amdgcn_cvt_pk_f32_fp8(u.y, false);
    f32x2 a3 = __builtin_amdgcn_cvt_pk_f32_fp8(u.y, true);
    f[0] = a0[0]; f[1] = a0[1]; f[2] = a1[0]; f[3] = a1[1];
    f[4] = a2[0]; f[5] = a2[1]; f[6] = a3[0]; f[7] = a3[1];
}
__device__ inline void fp8x4_to_f32(unsigned u, float* f) {
    f32x2 a0 = __builtin_amdgcn_cvt_pk_f32_fp8(u, false);
    f32x2 a1 = __builtin_amdgcn_cvt_pk_f32_fp8(u, true);
    f[0] = a0[0]; f[1] = a0[1]; f[2] = a1[0]; f[3] = a1[1];
}
__device__ inline unsigned char f32_to_fp8(float v) {
    return (unsigned char)__builtin_amdgcn_cvt_pk_fp8_f32(v, v, 0, false);
}

// ================= bucketed CSR build =================
// bucket b = dst >> 8 (256 nodes/bucket); record = (dstLow:8 << 17) | src:17

__global__ __launch_bounds__(1024) void kb_count(const int* __restrict__ dst,
                                                 int* __restrict__ bcount, int E) {
    __shared__ int cnt[16][512];   // per-wave banks, 32 KB
    const int tid = threadIdx.x;
    const int wv  = tid >> 6;
    for (int i = tid; i < 16 * 512; i += 1024) (&cnt[0][0])[i] = 0;
    __syncthreads();
#pragma unroll
    for (int q = 0; q < 8; ++q) {
        int i = blockIdx.x * 8192 + q * 1024 + tid;
        if (i < E) atomicAdd(&cnt[wv][dst[i] >> 8], 1);
    }
    __syncthreads();
    if (tid < 512) {
        int run = 0;
#pragma unroll
        for (int w = 0; w < 16; ++w) run += cnt[w][tid];
        if (run > 0) atomicAdd(&bcount[tid], run);
    }
}

__global__ __launch_bounds__(512) void k_scanb(const int* __restrict__ bcount,
                                               int* __restrict__ bbase,
                                               int* __restrict__ bcursor, int NB) {
    __shared__ int s[512];
    const int tid = threadIdx.x;
    int v = (tid < NB) ? bcount[tid] : 0;
    s[tid] = v;
    __syncthreads();
    int inc = v;
#pragma unroll
    for (int off = 1; off < 512; off <<= 1) {
        int add = (tid >= off) ? s[tid - off] : 0;
        __syncthreads();
        s[tid] = inc = inc + add;
        __syncthreads();
    }
    if (tid < NB) { bbase[tid] = inc - v; bcursor[tid] = inc - v; }
    if (tid == NB - 1) bbase[NB] = inc;
}

__global__ __launch_bounds__(1024) void kb_move(const int* __restrict__ src,
                                                const int* __restrict__ dst,
                                                int* __restrict__ bcursor,
                                                unsigned* __restrict__ recs, int E) {
    __shared__ int cnt[16][512];   // per-wave banks: counts -> wave prefixes -> cursors
    __shared__ int gbase[512];
    const int tid = threadIdx.x;
    const int wv  = tid >> 6;
    for (int i = tid; i < 16 * 512; i += 1024) (&cnt[0][0])[i] = 0;
    __syncthreads();

    int bq[8];
    unsigned rq[8];
#pragma unroll
    for (int q = 0; q < 8; ++q) {
        int i = blockIdx.x * 8192 + q * 1024 + tid;
        if (i < E) {
            int d = dst[i];
            int s = src[i];
            bq[q] = d >> 8;
            rq[q] = (unsigned)(((d & 255) << 17) | s);
            atomicAdd(&cnt[wv][bq[q]], 1);
        } else {
            bq[q] = -1;
            rq[q] = 0u;
        }
    }
    __syncthreads();
    if (tid < 512) {
        int run = 0;
#pragma unroll
        for (int w = 0; w < 16; ++w) {
            int t = cnt[w][tid];
            cnt[w][tid] = run;
            run += t;
        }
        gbase[tid] = (run > 0) ? atomicAdd(&bcursor[tid], run) : 0;
    }
    __syncthreads();
#pragma unroll
    for (int q = 0; q < 8; ++q) {
        if (bq[q] >= 0) {
            int p = gbase[bq[q]] + atomicAdd(&cnt[wv][bq[q]], 1);
            recs[p] = rq[q];
        }
    }
}

// one block (512 thr) per bucket: 2048-bin sort (dstLow<<3 | srcPartition)
// -> csr is partition-ordered within each node's segment (L2 phase locality).
__global__ __launch_bounds__(512) void kb_fill_lds(const unsigned* __restrict__ recs,
                                                   const int* __restrict__ bbase,
                                                   int* __restrict__ row_ptr,
                                                   float* __restrict__ dis,
                                                   int* __restrict__ csr, int n, int E) {
    __shared__ int hist[2048];
    __shared__ int wsum[512];
    __shared__ int base[2048];
    __shared__ int cur[2048];
    __shared__ int stage[FCAP];
    const int tid   = threadIdx.x;
    const int b     = blockIdx.x;
    const int s     = bbase[b], e = bbase[b + 1];
    const int nbase = b << 8;

    for (int i = tid; i < 2048; i += 512) hist[i] = 0;
    __syncthreads();
    for (int i = s + tid; i < e; i += 512) {
        unsigned r = recs[i];
        int dl = (int)(r >> 17);
        int sr = (int)(r & 0x1FFFFu);
        atomicAdd(&hist[(dl << 3) | (sr >> 14)], 1);
    }
    __syncthreads();

    // scan over 2048 bins: thread t owns bins 4t..4t+3
    const int l0 = hist[tid * 4 + 0];
    const int l1 = hist[tid * 4 + 1];
    const int l2 = hist[tid * 4 + 2];
    const int l3 = hist[tid * 4 + 3];
    const int tot = l0 + l1 + l2 + l3;
    wsum[tid] = tot;
    __syncthreads();
    int inc = tot;
#pragma unroll
    for (int off = 1; off < 512; off <<= 1) {
        int add = (tid >= off) ? wsum[tid - off] : 0;
        __syncthreads();
        wsum[tid] = inc = inc + add;
        __syncthreads();
    }
    int run = inc - tot;   // exclusive prefix of bin 4t
    base[tid * 4 + 0] = run; cur[tid * 4 + 0] = 0; run += l0;
    base[tid * 4 + 1] = run; cur[tid * 4 + 1] = 0; run += l1;
    base[tid * 4 + 2] = run; cur[tid * 4 + 2] = 0; run += l2;
    base[tid * 4 + 3] = run; cur[tid * 4 + 3] = 0; run += l3;
    __syncthreads();

    // row_ptr + dis at node level (node dl = bins dl*8..dl*8+7)
    if (tid < 256) {
        int cnt = 0;
#pragma unroll
        for (int q = 0; q < 8; ++q) cnt += hist[tid * 8 + q];
        const int idx = nbase + tid;
        if (idx < n) {
            row_ptr[idx] = s + base[tid * 8];
            dis[idx] = rsqrtf(1.0f + (float)cnt);
        }
        if (idx == n) row_ptr[n] = s + base[tid * 8];
        if (tid == 255 && nbase + 256 == n) row_ptr[n] = e;
    }
    __syncthreads();

    // place into LDS staging at sorted slot
    for (int i = s + tid; i < e; i += 512) {
        unsigned r = recs[i];
        int dl = (int)(r >> 17);
        int sr = (int)(r & 0x1FFFFu);
        int k  = (dl << 3) | (sr >> 14);
        int slot = base[k] + atomicAdd(&cur[k], 1);
        if (slot < FCAP) stage[slot] = sr;
        else csr[s + slot] = sr;
    }
    __syncthreads();

    const int total = e - s;
    const int lim = total < FCAP ? total : FCAP;
    for (int i = tid; i < lim; i += 512)
        csr[s + i] = stage[i];
}

// ================= weight prep: f32 [K][F] -> fp16 [F][K] =================
__global__ __launch_bounds__(256) void k_prep_w(const float* __restrict__ gW1,
                                                const float* __restrict__ mW1,
                                                const float* __restrict__ mW2,
                                                const float* __restrict__ gW2,
                                                _Float16* __restrict__ tg1,
                                                _Float16* __restrict__ tm1,
                                                _Float16* __restrict__ tm2,
                                                _Float16* __restrict__ tg2) {
    int i = blockIdx.x * 256 + threadIdx.x;
    if (i < 16384)      { int j = i;         int f = j >> 7, k = j & 127; tg1[j] = (_Float16)gW1[k * 128 + f]; }
    else if (i < 32768) { int j = i - 16384; int f = j >> 7, k = j & 127; tm1[j] = (_Float16)mW1[k * 128 + f]; }
    else if (i < 40960) { int j = i - 32768; int f = j >> 7, k = j & 127; tm2[j] = (_Float16)mW2[k * 64 + f]; }
    else if (i < 49152) { int j = i - 40960; int f = j >> 7, k = j & 127; tg2[j] = (_Float16)gW2[k * 64 + f]; }
}

// ============ fused MFMA: h1' = fp8(dis*(x@gW1)), z = relu(x@mW1+b1)@mW2+b2 ============
// LDS: As(16KB, aliased as Ms) + Ws(16KB half-staged) = 32 KB.
__global__ __launch_bounds__(256) void k_dual_mfma(const float* __restrict__ x,
                                                   const _Float16* __restrict__ tg1,
                                                   const _Float16* __restrict__ tm1,
                                                   const _Float16* __restrict__ tm2,
                                                   const float* __restrict__ b1,
                                                   const float* __restrict__ b2,
                                                   const float* __restrict__ dis,
                                                   unsigned char* __restrict__ h1,
                                                   _Float16* __restrict__ z, int nrows) {
    __shared__ _Float16 As[64 * 128];    // 16 KB (x fragments, later Ms)
    __shared__ _Float16 Ws[64 * 128];    // 16 KB (64 W rows at a time)
    _Float16* Ms = As;
    const int tid  = threadIdx.x;
    const int row0 = blockIdx.x * 64;

#pragma unroll
    for (int p = 0; p < 4; ++p) {
        int sid = p * 256 + tid;
        int r = sid >> 4, s = sid & 15;
        int gr = row0 + r;
        uint4 v = make_uint4(0, 0, 0, 0);
        if (gr < nrows) {
            const float4 f0 = *reinterpret_cast<const float4*>(x + (size_t)gr * 128 + s * 8);
            const float4 f1 = *reinterpret_cast<const float4*>(x + (size_t)gr * 128 + s * 8 + 4);
            _Float16 t[8] = {(_Float16)f0.x, (_Float16)f0.y, (_Float16)f0.z, (_Float16)f0.w,
                             (_Float16)f1.x, (_Float16)f1.y, (_Float16)f1.z, (_Float16)f1.w};
            v = *reinterpret_cast<uint4*>(t);
        }
        *reinterpret_cast<uint4*>(&As[r * 128 + ((s ^ (r & 7)) * 8)]) = v;
    }

    const int lane = tid & 63;
    const int wv   = tid >> 6;
    const int mrow = wv * 16 + (lane & 15);
    const int kg   = lane >> 4;
    const int grow = row0 + wv * 16 + kg * 4;

    auto stageW = [&](const _Float16* Wt, int wbase) {
#pragma unroll
        for (int p = 0; p < 4; ++p) {
            int sid = p * 256 + tid;
            int r = sid >> 4, s = sid & 15;
            uint4 v = *reinterpret_cast<const uint4*>(Wt + (size_t)(wbase + r) * 128 + s * 8);
            *reinterpret_cast<uint4*>(&Ws[r * 128 + ((s ^ (r & 7)) * 8)]) = v;
        }
    };

    stageW(tg1, 0);
    __syncthreads();

    half8 a[4];
#pragma unroll
    for (int kk = 0; kk < 4; ++kk)
        a[kk] = *reinterpret_cast<const half8*>(&As[mrow * 128 + (((kk * 4 + kg) ^ (mrow & 7)) * 8)]);

    float dvals[4];
#pragma unroll
    for (int j = 0; j < 4; ++j)
        dvals[j] = (grow + j < nrows) ? dis[grow + j] : 0.f;

    // phase 1: h1' = fp8(dis * (x @ gW1)), two column-half sub-phases
#pragma unroll
    for (int half = 0; half < 2; ++half) {
        if (half == 1) {
            __syncthreads();
            stageW(tg1, 64);
            __syncthreads();
        }
#pragma unroll
        for (int ct = 0; ct < 4; ++ct) {
            const int ncol = half * 64 + ct * 16 + (lane & 15);
            const int wrow = ncol & 63;
            f32x4 acc = {0.f, 0.f, 0.f, 0.f};
#pragma unroll
            for (int kk = 0; kk < 4; ++kk) {
                half8 b = *reinterpret_cast<const half8*>(&Ws[wrow * 128 + (((kk * 4 + kg) ^ (wrow & 7)) * 8)]);
                acc = __builtin_amdgcn_mfma_f32_16x16x32_f16(a[kk], b, acc, 0, 0, 0);
            }
#pragma unroll
            for (int j = 0; j < 4; ++j)
                if (grow + j < nrows)
                    h1[(size_t)(grow + j) * 128 + ncol] = f32_to_fp8(acc[j] * dvals[j]);
        }
    }
    __syncthreads();

    // phase 2: M = relu(x@mW1 + b1) -> Ms (=As region; a[] already in regs)
#pragma unroll
    for (int half = 0; half < 2; ++half) {
        stageW(tm1, half * 64);
        __syncthreads();
#pragma unroll
        for (int ct = 0; ct < 4; ++ct) {
            const int ncol = half * 64 + ct * 16 + (lane & 15);
            const int wrow = ncol & 63;
            f32x4 acc = {0.f, 0.f, 0.f, 0.f};
#pragma unroll
            for (int kk = 0; kk < 4; ++kk) {
                half8 b = *reinterpret_cast<const half8*>(&Ws[wrow * 128 + (((kk * 4 + kg) ^ (wrow & 7)) * 8)]);
                acc = __builtin_amdgcn_mfma_f32_16x16x32_f16(a[kk], b, acc, 0, 0, 0);
            }
            const float bias = b1[ncol];
#pragma unroll
            for (int j = 0; j < 4; ++j) {
                int r = wv * 16 + kg * 4 + j;
                float v = fmaxf((float)acc[j] + bias, 0.f);
                Ms[r * 128 + (((ncol >> 3) ^ (r & 7)) * 8) + (ncol & 7)] = (_Float16)v;
            }
        }
        __syncthreads();
    }

    // phase 3: z = M @ mW2 + b2 (F=64)
    stageW(tm2, 0);
    __syncthreads();

    half8 am[4];
#pragma unroll
    for (int kk = 0; kk < 4; ++kk)
        am[kk] = *reinterpret_cast<const half8*>(&Ms[mrow * 128 + (((kk * 4 + kg) ^ (mrow & 7)) * 8)]);

#pragma unroll
    for (int ct = 0; ct < 4; ++ct) {
        const int ncol = ct * 16 + (lane & 15);
        f32x4 acc = {0.f, 0.f, 0.f, 0.f};
#pragma unroll
        for (int kk = 0; kk < 4; ++kk) {
            half8 b = *reinterpret_cast<const half8*>(&Ws[ncol * 128 + (((kk * 4 + kg) ^ (ncol & 7)) * 8)]);
            acc = __builtin_amdgcn_mfma_f32_16x16x32_f16(am[kk], b, acc, 0, 0, 0);
        }
        const float bias = b2[ncol];
#pragma unroll
        for (int j = 0; j < 4; ++j)
            if (grow + j < nrows)
                z[(size_t)(grow + j) * 64 + ncol] = (_Float16)((float)acc[j] + bias);
    }
}

// ============ MFMA GEMM: h2' = fp8(dis * (hmid @ gW2)), F=64; W in LDS ============
__global__ __launch_bounds__(256) void k_mm64(const _Float16* __restrict__ A,
                                              const _Float16* __restrict__ Wt,
                                              const float* __restrict__ dis,
                                              unsigned char* __restrict__ C, int nrows) {
    __shared__ _Float16 As[64 * 128];
    __shared__ _Float16 Ws[64 * 128];
    const int tid  = threadIdx.x;
    const int row0 = blockIdx.x * 64;

#pragma unroll
    for (int p = 0; p < 4; ++p) {
        int sid = p * 256 + tid;
        int r = sid >> 4, s = sid & 15;
        int gr = row0 + r;
        uint4 v = make_uint4(0, 0, 0, 0);
        if (gr < nrows) v = *reinterpret_cast<const uint4*>(A + (size_t)gr * 128 + s * 8);
        *reinterpret_cast<uint4*>(&As[r * 128 + ((s ^ (r & 7)) * 8)]) = v;
    }
#pragma unroll
    for (int p = 0; p < 4; ++p) {
        int sid = p * 256 + tid;
        int r = sid >> 4, s = sid & 15;
        uint4 v = *reinterpret_cast<const uint4*>(Wt + (size_t)r * 128 + s * 8);
        *reinterpret_cast<uint4*>(&Ws[r * 128 + ((s ^ (r & 7)) * 8)]) = v;
    }
    __syncthreads();

    const int lane = tid & 63;
    const int wv   = tid >> 6;
    const int mrow = wv * 16 + (lane & 15);
    const int kg   = lane >> 4;
    const int grow = row0 + wv * 16 + kg * 4;

    half8 a[4];
#pragma unroll
    for (int kk = 0; kk < 4; ++kk)
        a[kk] = *reinterpret_cast<const half8*>(&As[mrow * 128 + (((kk * 4 + kg) ^ (mrow & 7)) * 8)]);

    float dvals[4];
#pragma unroll
    for (int j = 0; j < 4; ++j)
        dvals[j] = (grow + j < nrows) ? dis[grow + j] : 0.f;

#pragma unroll
    for (int ct = 0; ct < 4; ++ct) {
        const int ncol = ct * 16 + (lane & 15);
        f32x4 acc = {0.f, 0.f, 0.f, 0.f};
#pragma unroll
        for (int kk = 0; kk < 4; ++kk) {
            half8 b = *reinterpret_cast<const half8*>(&Ws[ncol * 128 + (((kk * 4 + kg) ^ (ncol & 7)) * 8)]);
            acc = __builtin_amdgcn_mfma_f32_16x16x32_f16(a[kk], b, acc, 0, 0, 0);
        }
#pragma unroll
        for (int j = 0; j < 4; ++j)
            if (grow + j < nrows)
                C[(size_t)(grow + j) * 64 + ncol] = f32_to_fp8(acc[j] * dvals[j]);
    }
}

// ================= gather aggregation — serial partition-ordered walk, unroll 4 =================
// layer 1: 16 nodes/block, one 16-lane group per node, consecutive-edge unroll-4.
__global__ __launch_bounds__(256) void k_agg1(const int* __restrict__ rp,
                                              const int* __restrict__ csr,
                                              const float* __restrict__ dis,
                                              const unsigned char* __restrict__ h1,
                                              const float* __restrict__ b,
                                              _Float16* __restrict__ out, int n) {
    const int tid  = threadIdx.x;
    const int node = blockIdx.x * 16 + (tid >> 4);
    if (node >= n) return;
    const int c0 = (tid & 15) * 8;    // 8 fp8 bytes per lane
    const int start = rp[node], end = rp[node + 1];

    f32x2 acc[4] = {{0.f, 0.f}, {0.f, 0.f}, {0.f, 0.f}, {0.f, 0.f}};

    int j = start;
    for (; j + 3 < end; j += 4) {
        int s0 = csr[j];
        int s1 = csr[j + 1];
        int s2 = csr[j + 2];
        int s3 = csr[j + 3];
        uint2 u0 = *reinterpret_cast<const uint2*>(h1 + (size_t)s0 * 128 + c0);
        uint2 u1 = *reinterpret_cast<const uint2*>(h1 + (size_t)s1 * 128 + c0);
        uint2 u2 = *reinterpret_cast<const uint2*>(h1 + (size_t)s2 * 128 + c0);
        uint2 u3 = *reinterpret_cast<const uint2*>(h1 + (size_t)s3 * 128 + c0);
        acc_fp8x8(u0, acc);
        acc_fp8x8(u1, acc);
        acc_fp8x8(u2, acc);
        acc_fp8x8(u3, acc);
    }
    for (; j < end; ++j) {
        int s0 = csr[j];
        uint2 u0 = *reinterpret_cast<const uint2*>(h1 + (size_t)s0 * 128 + c0);
        acc_fp8x8(u0, acc);
    }

    const float dd = dis[node];
    uint2 un = *reinterpret_cast<const uint2*>(h1 + (size_t)node * 128 + c0);
    float fn[8];
    fp8x8_to_f32(un, fn);
    const float av[8] = {acc[0][0], acc[0][1], acc[1][0], acc[1][1],
                         acc[2][0], acc[2][1], acc[3][0], acc[3][1]};
    const float4 bv0 = *reinterpret_cast<const float4*>(b + c0);
    const float4 bv1 = *reinterpret_cast<const float4*>(b + c0 + 4);
    const float bb[8] = {bv0.x, bv0.y, bv0.z, bv0.w, bv1.x, bv1.y, bv1.z, bv1.w};
    half8 o;
#pragma unroll
    for (int k = 0; k < 8; ++k)
        o[k] = (_Float16)fmaxf(dd * (av[k] + fn[k]) + bb[k], 0.f);
    *reinterpret_cast<half8*>(out + (size_t)node * 128 + c0) = o;
}

// layer 2 + final fuse: 16 nodes/block, 16-lane groups, consecutive-edge unroll-4.
__global__ __launch_bounds__(256) void k_agg2(const int* __restrict__ rp,
                                              const int* __restrict__ csr,
                                              const float* __restrict__ dis,
                                              const unsigned char* __restrict__ h2,
                                              const float* __restrict__ b,
                                              const _Float16* __restrict__ zmlp,
                                              float* __restrict__ out, int n) {
    const int tid  = threadIdx.x;
    const int node = blockIdx.x * 16 + (tid >> 4);
    if (node >= n) return;
    const int c0 = (tid & 15) * 4;    // 4 fp8 bytes per lane
    const int start = rp[node], end = rp[node + 1];

    f32x2 acc[2] = {{0.f, 0.f}, {0.f, 0.f}};

    int j = start;
    for (; j + 3 < end; j += 4) {
        int s0 = csr[j];
        int s1 = csr[j + 1];
        int s2 = csr[j + 2];
        int s3 = csr[j + 3];
        unsigned u0 = *reinterpret_cast<const unsigned*>(h2 + (size_t)s0 * 64 + c0);
        unsigned u1 = *reinterpret_cast<const unsigned*>(h2 + (size_t)s1 * 64 + c0);
        unsigned u2 = *reinterpret_cast<const unsigned*>(h2 + (size_t)s2 * 64 + c0);
        unsigned u3 = *reinterpret_cast<const unsigned*>(h2 + (size_t)s3 * 64 + c0);
        acc_fp8x4(u0, acc);
        acc_fp8x4(u1, acc);
        acc_fp8x4(u2, acc);
        acc_fp8x4(u3, acc);
    }
    for (; j < end; ++j) {
        int s0 = csr[j];
        unsigned u0 = *reinterpret_cast<const unsigned*>(h2 + (size_t)s0 * 64 + c0);
        acc_fp8x4(u0, acc);
    }

    const float dd = dis[node];
    unsigned un = *reinterpret_cast<const unsigned*>(h2 + (size_t)node * 64 + c0);
    float fn[4];
    fp8x4_to_f32(un, fn);
    const float av[4] = {acc[0][0], acc[0][1], acc[1][0], acc[1][1]};
    half4 zm = *reinterpret_cast<const half4*>(zmlp + (size_t)node * 64 + c0);
    const float4 bv = *reinterpret_cast<const float4*>(b + c0);
    const float bb[4] = {bv.x, bv.y, bv.z, bv.w};
    float4 o;
    float* op = &o.x;
#pragma unroll
    for (int k = 0; k < 4; ++k)
        op[k] = 0.5f * ((dd * (av[k] + fn[k]) + bb[k]) + (float)zm[k]);
    *reinterpret_cast<float4*>(out + (size_t)node * 64 + c0) = o;
}

extern "C" void kernel_launch(void* const* d_in, const int* in_sizes, int n_in,
                              void* d_out, int out_size, void* d_ws, size_t ws_size,
                              hipStream_t stream) {
    const float* x      = (const float*)d_in[0];
    const int* edge_idx = (const int*)d_in[1];
    const float* gnn_W1 = (const float*)d_in[2];
    const float* gnn_b1 = (const float*)d_in[3];
    const float* gnn_W2 = (const float*)d_in[4];
    const float* gnn_b2 = (const float*)d_in[5];
    const float* mlp_W1 = (const float*)d_in[6];
    const float* mlp_b1 = (const float*)d_in[7];
    const float* mlp_W2 = (const float*)d_in[8];
    const float* mlp_b2 = (const float*)d_in[9];
    float* out = (float*)d_out;

    const int N = in_sizes[0] / IN_F;
    const int E = in_sizes[1] / 2;
    const int* src = edge_idx;
    const int* dst = edge_idx + E;

    const int NB = (N + 255) >> 8;   // 256-node buckets

    // ---- workspace layout ----
    char* wp = (char*)d_ws;
    int* row_ptr   = (int*)wp;            wp += ((size_t)N + 4) * sizeof(int);
    int* bbase     = (int*)wp;            wp += 516 * sizeof(int);
    int* bcursor   = (int*)wp;            wp += 512 * sizeof(int);
    int* bcount    = (int*)wp;            wp += 512 * sizeof(int);
    int* csr       = (int*)wp;            wp += (size_t)E * sizeof(int);
    unsigned* recs = (unsigned*)wp;       wp += (size_t)E * sizeof(unsigned);
    float* dis     = (float*)wp;          wp += (size_t)N * sizeof(float);
    _Float16* tg1  = (_Float16*)wp;       wp += 16384 * sizeof(_Float16);
    _Float16* tm1  = (_Float16*)wp;       wp += 16384 * sizeof(_Float16);
    _Float16* tm2  = (_Float16*)wp;       wp += 8192 * sizeof(_Float16);
    _Float16* tg2  = (_Float16*)wp;       wp += 8192 * sizeof(_Float16);
    unsigned char* h1 = (unsigned char*)wp;  wp += (size_t)N * 128;            // fp8
    _Float16* hmid = (_Float16*)wp;       wp += (size_t)N * 128 * sizeof(_Float16);
    unsigned char* h2 = (unsigned char*)wp;  wp += (size_t)N * 64;             // fp8
    wp = (char*)(((uintptr_t)wp + 15) & ~(uintptr_t)15);
    _Float16* zmlp = (_Float16*)wp;       wp += (size_t)N * 64 * sizeof(_Float16);

    // ---- weight prep ----
    k_prep_w<<<192, 256, 0, stream>>>(gnn_W1, mlp_W1, mlp_W2, gnn_W2, tg1, tm1, tm2, tg2);

    // ---- bucketed CSR build (partition-ordered within node) ----
    hipMemsetAsync(bcount, 0, 512 * sizeof(int), stream);
    const int mvblocks = (E + 8191) / 8192;
    kb_count<<<mvblocks, 1024, 0, stream>>>(dst, bcount, E);
    k_scanb<<<1, 512, 0, stream>>>(bcount, bbase, bcursor, NB);
    kb_move<<<mvblocks, 1024, 0, stream>>>(src, dst, bcursor, recs, E);
    kb_fill_lds<<<NB, 512, 0, stream>>>(recs, bbase, row_ptr, dis, csr, N, E);

    const int gblocks = (N + 63) / 64;
    const int ablocks = (N + 15) / 16;

    // ---- fused: h1' = fp8(dis*(x@gW1)), zmlp = MLP(x) (one x pass; 32KB LDS) ----
    k_dual_mfma<<<gblocks, 256, 0, stream>>>(x, tg1, tm1, tm2, mlp_b1, mlp_b2, dis, h1, zmlp, N);

    // ---- GNN layer 1 aggregation (serial partition-ordered, 4 edges in flight) ----
    k_agg1<<<ablocks, 256, 0, stream>>>(row_ptr, csr, dis, h1, gnn_b1, hmid, N);

    // ---- h2' = fp8(dis*(hmid @ gW2)) (MFMA) ----
    k_mm64<<<gblocks, 256, 0, stream>>>(hmid, tg2, dis, h2, N);

    // ---- layer-2 aggregation fused with final mix ----
    k_agg2<<<ablocks, 256, 0, stream>>>(row_ptr, csr, dis, h2, gnn_b2, zmlp, out, N);
}